// Round 9
// baseline (536.919 us; speedup 1.0000x reference)
//
#include <hip/hip_runtime.h>

// Quantize_78365973283370: VQ with argmax (faithful source bug: farthest cluster).
// d_in[0] = inputs [8,32,32,128] f32 (N=8192 x D=128)
// d_in[1] = cluster_mean [128,10000] f32 (column e = cluster vector)
// out (f32 concat): quantize[8192*128] | cluster_index[8192] (as float) | diff[8192]
//
// R7: LDS-free hot loop. Samples pre-transposed to sT[d][8192] so per-d sample values
// are wave-uniform 64B rows -> scalar s_load (K$), no ds_read, no LDS pipe pressure.
// NE=2 cols/thread keeps regs ~100 (no spills at 4 waves/SIMD). Grid doubled by
// splitting the e-range in half per block (1024 blocks x 512 thr); per-block top-2
// partials merged by a small kernel; flagged samples (gap < MARGIN) refined exactly
// in f64 by early-exit per-sample blocks (matches R1's proven-exact result).

#define NSAMP 8192
#define NEMB  10000
#define DIM   128
#define NS    16            // samples per block
#define TPB   512
#define HALF  (NEMB / 2)    // 5000 columns per e-half
#define CHUNK1 (TPB * 2)    // 1024 columns per chunk (2 cols/thread)
#define MARGIN 0.02f

// ---------------- prep: cluster norms in f64 (+f32 copy) ----------------
__global__ __launch_bounds__(256) void prep_c2(const float* __restrict__ cm,
                                               double* __restrict__ c2d,
                                               float* __restrict__ c2f) {
    int e = blockIdx.x * 256 + threadIdx.x;
    if (e >= NEMB) return;
    double a = 0.0;
#pragma unroll 8
    for (int d = 0; d < DIM; ++d) {
        double v = (double)cm[(size_t)d * NEMB + e];
        a = fma(v, v, a);
    }
    c2d[e] = a;
    c2f[e] = (float)a;
}

// ---------------- prep: transpose samples to sT[d][n] (LDS-tiled) ----------------
__global__ __launch_bounds__(256) void prep_sT(const float* __restrict__ smp,
                                               float* __restrict__ sT) {
    __shared__ float t[64][65];
    const int tid = threadIdx.x;
    const int bn = blockIdx.x & 127;        // n-tile (8192/64 = 128)
    const int bd = blockIdx.x >> 7;         // d-tile (128/64 = 2)
    const int n0 = bn * 64, d0 = bd * 64;
#pragma unroll
    for (int i = 0; i < 4; ++i) {
        int nloc = (tid >> 4) + i * 16;
        int dl4  = (tid & 15) * 4;
        float4 v = *(const float4*)&smp[(size_t)(n0 + nloc) * DIM + d0 + dl4];
        t[dl4 + 0][nloc] = v.x; t[dl4 + 1][nloc] = v.y;
        t[dl4 + 2][nloc] = v.z; t[dl4 + 3][nloc] = v.w;
    }
    __syncthreads();
#pragma unroll
    for (int i = 0; i < 4; ++i) {
        int dloc = (tid >> 4) + i * 16;
        int nl4  = (tid & 15) * 4;
        float4 w = make_float4(t[dloc][nl4], t[dloc][nl4 + 1], t[dloc][nl4 + 2], t[dloc][nl4 + 3]);
        *(float4*)&sT[(size_t)(d0 + dloc) * NSAMP + n0 + nl4] = w;
    }
}

// ---------------- K1: f32 partial scan (per sample-group x e-half) ----------------
__global__ __launch_bounds__(TPB, 4) void vq_partial(
    const float* __restrict__ cm, const float* __restrict__ sT,
    const float* __restrict__ c2f,
    float* __restrict__ pv1, float* __restrict__ pv2, int* __restrict__ pi1)
{
    const int tid = threadIdx.x;
    const int sg   = blockIdx.x >> 1;       // sample group (512)
    const int half = blockIdx.x & 1;        // e-half
    const int s0 = sg * NS;
    const int ebeg = half * HALF, eend = ebeg + HALF;
    const int lane = tid & 63, wav = tid >> 6;

    float v1[NS], v2[NS];
    int   i1[NS];
#pragma unroll
    for (int s = 0; s < NS; ++s) { v1[s] = -3.0e38f; v2[s] = -3.0e38f; i1[s] = 0; }

#pragma unroll 1
    for (int e0 = ebeg; e0 < eend; e0 += CHUNK1) {      // 5 chunks (last partial)
        const int b0 = e0 + tid * 2;
        const int cb0 = (b0 > eend - 2) ? (eend - 2) : b0;   // clamp tail (even, 8B-aligned)
        const float* p0 = cm + cb0;

        float acc0[NS], acc1[NS];
#pragma unroll
        for (int s = 0; s < NS; ++s) { acc0[s] = 0.0f; acc1[s] = 0.0f; }

#pragma unroll 4
        for (int d = 0; d < DIM; ++d) {
            float2 cv = *(const float2*)(p0 + (size_t)d * NEMB);
            const float* sd = sT + (size_t)d * NSAMP + s0;   // wave-uniform -> s_load
#pragma unroll
            for (int s = 0; s < NS; ++s) {
                float sv = sd[s];
                acc0[s] = fmaf(cv.x, sv, acc0[s]);
                acc1[s] = fmaf(cv.y, sv, acc1[s]);
            }
        }

        float2 c0 = *(const float2*)(c2f + cb0);
        const int e_c0 = b0, e_c1 = b0 + 1;                  // ascending
        if (e_c0 < eend) {
#pragma unroll
            for (int s = 0; s < NS; ++s) {
                float sc = fmaf(-2.0f, acc0[s], c0.x);
                if (sc > v1[s]) { v2[s] = v1[s]; v1[s] = sc; i1[s] = e_c0; }
                else if (sc > v2[s]) { v2[s] = sc; }
            }
        }
        if (e_c1 < eend) {
#pragma unroll
            for (int s = 0; s < NS; ++s) {
                float sc = fmaf(-2.0f, acc1[s], c0.y);
                if (sc > v1[s]) { v2[s] = v1[s]; v1[s] = sc; i1[s] = e_c1; }
                else if (sc > v2[s]) { v2[s] = sc; }
            }
        }
    }

    // wave butterfly merge: max val (tie -> smaller idx), track second-max
#pragma unroll
    for (int s = 0; s < NS; ++s) {
#pragma unroll
        for (int m = 1; m < 64; m <<= 1) {
            float ov1 = __shfl_xor(v1[s], m, 64);
            int   oi1 = __shfl_xor(i1[s], m, 64);
            float ov2 = __shfl_xor(v2[s], m, 64);
            float nv2 = fmaxf(fminf(v1[s], ov1), fmaxf(v2[s], ov2));
            if (ov1 > v1[s] || (ov1 == v1[s] && oi1 < i1[s])) { v1[s] = ov1; i1[s] = oi1; }
            v2[s] = nv2;
        }
    }

    __shared__ float swv1[TPB / 64][NS], swv2[TPB / 64][NS];
    __shared__ int   swi[TPB / 64][NS];
    if (lane == 0) {
#pragma unroll
        for (int s = 0; s < NS; ++s) { swv1[wav][s] = v1[s]; swi[wav][s] = i1[s]; swv2[wav][s] = v2[s]; }
    }
    __syncthreads();
    if (tid < NS) {
        const int s = tid;
        float bv1 = swv1[0][s]; int bi = swi[0][s]; float bv2 = swv2[0][s];
#pragma unroll
        for (int w = 1; w < TPB / 64; ++w) {
            float av1 = swv1[w][s]; int ai = swi[w][s]; float av2 = swv2[w][s];
            float nv2 = fmaxf(fminf(bv1, av1), fmaxf(bv2, av2));
            if (av1 > bv1 || (av1 == bv1 && ai < bi)) { bv1 = av1; bi = ai; }
            bv2 = nv2;
        }
        pv1[blockIdx.x * NS + s] = bv1;
        pv2[blockIdx.x * NS + s] = bv2;
        pi1[blockIdx.x * NS + s] = bi;
    }
}

// ---------------- K2: merge halves + gather + diff ----------------
__global__ __launch_bounds__(128) void vq_merge(
    const float* __restrict__ cm, const float* __restrict__ smp,
    const float* __restrict__ pv1, const float* __restrict__ pv2, const int* __restrict__ pi1,
    float* __restrict__ out_q, float* __restrict__ out_idx, float* __restrict__ out_diff,
    int* __restrict__ flag)
{
    const int s = blockIdx.x;
    const int tid = threadIdx.x;          // = d
    const int sg = s >> 4, j = s & 15;
    const int pa = (sg * 2) * NS + j, pb = (sg * 2 + 1) * NS + j;

    // all threads compute the (tiny) merge redundantly — broadcast loads
    float v1a = pv1[pa], v2a = pv2[pa]; int i1a = pi1[pa];
    float v1b = pv1[pb], v2b = pv2[pb]; int i1b = pi1[pb];
    float bv1; int bi;
    if (v1b > v1a) { bv1 = v1b; bi = i1b; } else { bv1 = v1a; bi = i1a; }  // tie -> a (smaller e)
    float bv2 = fmaxf(fminf(v1a, v1b), fmaxf(v2a, v2b));

    if (tid == 0) {
        out_idx[s] = (float)bi;
        flag[s] = (bv1 - bv2 < MARGIN) ? 1 : 0;
    }

    // gather + diff (d = tid)
    float q = cm[(size_t)tid * NEMB + bi];
    float x = smp[(size_t)s * DIM + tid];
    out_q[(size_t)s * DIM + tid] = q;
    float t = x - q;
    float t2 = t * t;
#pragma unroll
    for (int m = 1; m < 64; m <<= 1) t2 += __shfl_xor(t2, m, 64);
    __shared__ float ws2[2];
    if ((tid & 63) == 0) ws2[tid >> 6] = t2;
    __syncthreads();
    if (tid == 0) out_diff[s] = (ws2[0] + ws2[1]) * (1.0f / DIM);
}

// ---------------- K3: exact f64 refine, one sample per block, early exit ----------------
__global__ __launch_bounds__(256) void vq_refine(
    const float* __restrict__ cm, const float* __restrict__ smp,
    const double* __restrict__ c2d, const int* __restrict__ flag,
    float* __restrict__ out_q, float* __restrict__ out_idx, float* __restrict__ out_diff)
{
    const int s = blockIdx.x;
    if (!flag[s]) return;
    const int tid = threadIdx.x;
    const int lane = tid & 63, wav = tid >> 6;

    __shared__ double svd[DIM];
    __shared__ double rwv[4];
    __shared__ int    rwe[4];
    __shared__ float  dsum[4];
    __shared__ int    fin;

    if (tid < DIM) svd[tid] = (double)smp[(size_t)s * DIM + tid];
    __syncthreads();

    double bv = -1.0e300; int be = 0;
#pragma unroll 1
    for (int e0 = tid * 4; e0 < NEMB; e0 += 256 * 4) {     // ascending e per thread
        double dot[4] = {0.0, 0.0, 0.0, 0.0};
#pragma unroll 8
        for (int d = 0; d < DIM; ++d) {
            float4 cv = *(const float4*)(cm + (size_t)d * NEMB + e0);
            double sd = svd[d];
            dot[0] = fma((double)cv.x, sd, dot[0]);
            dot[1] = fma((double)cv.y, sd, dot[1]);
            dot[2] = fma((double)cv.z, sd, dot[2]);
            dot[3] = fma((double)cv.w, sd, dot[3]);
        }
#pragma unroll
        for (int k = 0; k < 4; ++k) {
            int e = e0 + k;
            double sc = fma(-2.0, dot[k], c2d[e]);
            if (sc > bv) { bv = sc; be = e; }
        }
    }
#pragma unroll
    for (int m = 1; m < 64; m <<= 1) {
        double ov = __shfl_xor(bv, m, 64);
        int    oe = __shfl_xor(be, m, 64);
        if (ov > bv || (ov == bv && oe < be)) { bv = ov; be = oe; }
    }
    if (lane == 0) { rwv[wav] = bv; rwe[wav] = be; }
    __syncthreads();
    if (tid == 0) {
        double v = rwv[0]; int e = rwe[0];
#pragma unroll
        for (int w = 1; w < 4; ++w)
            if (rwv[w] > v || (rwv[w] == v && rwe[w] < e)) { v = rwv[w]; e = rwe[w]; }
        fin = e;
        out_idx[s] = (float)e;
    }
    __syncthreads();
    const int e = fin;
    float t2 = 0.0f;
    if (tid < DIM) {
        float q = cm[(size_t)tid * NEMB + e];
        float x = smp[(size_t)s * DIM + tid];
        out_q[(size_t)s * DIM + tid] = q;
        float t = x - q;
        t2 = t * t;
    }
#pragma unroll
    for (int m = 1; m < 64; m <<= 1) t2 += __shfl_xor(t2, m, 64);
    if (lane == 0) dsum[wav] = t2;
    __syncthreads();
    if (tid == 0) out_diff[s] = (dsum[0] + dsum[1] + dsum[2] + dsum[3]) * (1.0f / DIM);
}

extern "C" void kernel_launch(void* const* d_in, const int* in_sizes, int n_in,
                              void* d_out, int out_size, void* d_ws, size_t ws_size,
                              hipStream_t stream) {
    const float* smp = (const float*)d_in[0];   // [8192,128]
    const float* cm  = (const float*)d_in[1];   // [128,10000]

    float* out      = (float*)d_out;
    float* out_q    = out;
    float* out_idx  = out + (size_t)NSAMP * DIM;
    float* out_diff = out_idx + NSAMP;

    char* ws = (char*)d_ws;
    double* c2d = (double*)ws;                               // 80000 B
    float*  c2f = (float*)(ws + 80000);                      // 40000 B
    float*  sT  = (float*)(ws + 120064);                     // 4 MB, 16B aligned
    float*  pv1 = (float*)(ws + 120064 + 4194304);           // 1024*16*4 = 65536
    float*  pv2 = (float*)(ws + 120064 + 4194304 + 65536);
    int*    pi1 = (int*)  (ws + 120064 + 4194304 + 131072);
    int*    flag= (int*)  (ws + 120064 + 4194304 + 196608);  // 32768

    prep_c2<<<(NEMB + 255) / 256, 256, 0, stream>>>(cm, c2d, c2f);
    prep_sT<<<256, 256, 0, stream>>>(smp, sT);
    vq_partial<<<(NSAMP / NS) * 2, TPB, 0, stream>>>(cm, sT, c2f, pv1, pv2, pi1);
    vq_merge<<<NSAMP, 128, 0, stream>>>(cm, smp, pv1, pv2, pi1, out_q, out_idx, out_diff, flag);
    vq_refine<<<NSAMP, 256, 0, stream>>>(cm, smp, c2d, flag, out_q, out_idx, out_diff);
}